// Round 1
// baseline (244.605 us; speedup 1.0000x reference)
//
#include <hip/hip_runtime.h>

#define N_NODES 4096
#define D_DIM   512
#define E_EDGES 131072
#define NWORDS  128   // 4096 / 32

typedef __bf16 bf16;
typedef __bf16 bf16x4 __attribute__((ext_vector_type(4)));
typedef __bf16 bf16x8 __attribute__((ext_vector_type(8)));
typedef float  f32x4  __attribute__((ext_vector_type(4)));

// ---------------- workspace layout (bytes) ----------------
static const size_t OFF_XB  = 0;                      // coeffs bf16   4 MiB
static const size_t OFF_W0B = OFF_XB  + 4194304;      // W0 bf16       512 KiB
static const size_t OFF_W1B = OFF_W0B + 524288;
static const size_t OFF_W2B = OFF_W1B + 524288;
static const size_t OFF_X1  = OFF_W2B + 524288;       // x1 bf16       4 MiB
static const size_t OFF_X2  = OFF_X1  + 4194304;      // x2 bf16       4 MiB
static const size_t OFF_X3  = OFF_X2  + 4194304;      // x3 fp32       8 MiB
static const size_t OFF_ANG = OFF_X3  + 8388608;      // angles fp32   16 KiB
static const size_t OFF_A1  = OFF_ANG + 16384;        // a1 fp32
static const size_t OFF_A2V = OFF_A1  + 16384;        // a2 fp32
static const size_t OFF_AB  = OFF_A2V + 16384;        // A bits        2 MiB
static const size_t OFF_A2B = OFF_AB  + 2097152;      // A^2 bits      2 MiB
static const size_t OFF_A3B = OFF_A2B + 2097152;      // A^3 bits      2 MiB

// ---------------- cast fp32 -> bf16 ----------------
__global__ void cast_f32_bf16(const float* __restrict__ in, bf16* __restrict__ out, int n) {
    int i = (blockIdx.x * blockDim.x + threadIdx.x) * 4;
    if (i < n) {
        float4 v = *(const float4*)(in + i);
        bf16x4 o;
        o.x = (bf16)v.x; o.y = (bf16)v.y; o.z = (bf16)v.z; o.w = (bf16)v.w;
        *(bf16x4*)(out + i) = o;
    }
}

// ---------------- bf16 MFMA GEMM: C[m][n] = sum_k X[m][k] * W[n][k] ----------------
// 128x128 tile, BK=32, 256 threads = 4 waves (2x2 of 64x64), 16x16x32 MFMA.
template<bool HAS_BIAS, bool OUT_F32>
__global__ __launch_bounds__(256)
void gemm_bt(const bf16* __restrict__ X, const bf16* __restrict__ W,
             bf16* __restrict__ outB, float* __restrict__ outF,
             const float* __restrict__ bias, const float* __restrict__ slope)
{
    __shared__ bf16 At[128][32];
    __shared__ bf16 Bt[128][32];
    const int t    = threadIdx.x;
    const int wave = t >> 6, lane = t & 63;
    const int wm   = wave >> 1, wn = wave & 1;
    const int quad = lane >> 4, lq = lane & 15;
    const int rowBase = blockIdx.x * 128;
    const int colBase = blockIdx.y * 128;

    f32x4 acc[4][4] = {};

    for (int k0 = 0; k0 < D_DIM; k0 += 32) {
        // stage A and B tiles: 512 chunks of 8 bf16 each, 2 chunks per thread
        #pragma unroll
        for (int s = 0; s < 2; ++s) {
            int c = t + s * 256;
            int r = c >> 2, cc = (c & 3) * 8;
            *(uint4*)&At[r][cc] = *(const uint4*)&X[(size_t)(rowBase + r) * D_DIM + k0 + cc];
            *(uint4*)&Bt[r][cc] = *(const uint4*)&W[(size_t)(colBase + r) * D_DIM + k0 + cc];
        }
        __syncthreads();

        bf16x8 af[4], bfr[4];
        #pragma unroll
        for (int tm = 0; tm < 4; ++tm)
            af[tm] = *(const bf16x8*)&At[wm * 64 + tm * 16 + lq][quad * 8];
        #pragma unroll
        for (int tn = 0; tn < 4; ++tn)
            bfr[tn] = *(const bf16x8*)&Bt[wn * 64 + tn * 16 + lq][quad * 8];

        #pragma unroll
        for (int tm = 0; tm < 4; ++tm)
            #pragma unroll
            for (int tn = 0; tn < 4; ++tn)
                acc[tm][tn] = __builtin_amdgcn_mfma_f32_16x16x32_bf16(af[tm], bfr[tn], acc[tm][tn], 0, 0, 0);
        __syncthreads();
    }

    const float a = slope[0];
    #pragma unroll
    for (int tm = 0; tm < 4; ++tm) {
        #pragma unroll
        for (int tn = 0; tn < 4; ++tn) {
            int col = colBase + wn * 64 + tn * 16 + lq;
            float b = HAS_BIAS ? bias[col] : 0.f;
            #pragma unroll
            for (int r = 0; r < 4; ++r) {
                int row = rowBase + wm * 64 + tm * 16 + quad * 4 + r;
                float v = acc[tm][tn][r] + b;
                v = (v >= 0.f) ? v : a * v;
                if (OUT_F32) outF[(size_t)row * D_DIM + col] = v;
                else         outB[(size_t)row * D_DIM + col] = (bf16)v;
            }
        }
    }
}

// ---------------- final matvec: angles[r] = x3[r,:] . Wo + bo; also seeds a1 ----------------
__global__ void matvec_out(const float* __restrict__ X, const float* __restrict__ Wo,
                           const float* __restrict__ bo, float* __restrict__ angles,
                           float* __restrict__ a1)
{
    int row  = blockIdx.x * 4 + (threadIdx.x >> 6);
    int lane = threadIdx.x & 63;
    const float4* xp = (const float4*)(X + (size_t)row * D_DIM);
    const float4* wp = (const float4*)Wo;
    float s = 0.f;
    #pragma unroll
    for (int i = 0; i < 2; ++i) {
        float4 x = xp[i * 64 + lane];
        float4 w = wp[i * 64 + lane];
        s += x.x * w.x + x.y * w.y + x.z * w.z + x.w * w.w;
    }
    #pragma unroll
    for (int off = 32; off > 0; off >>= 1) s += __shfl_down(s, off, 64);
    if (lane == 0) { float v = s + bo[0]; angles[row] = v; a1[row] = v; }
}

// ---------------- hop 1: raw edge list, duplicates count ----------------
__global__ void hop1_edges(const int* __restrict__ src, const int* __restrict__ dst,
                           const float* __restrict__ angles, float* __restrict__ a1)
{
    int e = blockIdx.x * blockDim.x + threadIdx.x;
    if (e < E_EDGES) atomicAdd(&a1[src[e]], 0.25f * angles[dst[e]]);
}

// ---------------- build boolean adjacency bitmatrix ----------------
__global__ void build_adj(const int* __restrict__ src, const int* __restrict__ dst,
                          unsigned int* __restrict__ A)
{
    int e = blockIdx.x * blockDim.x + threadIdx.x;
    if (e < E_EDGES) {
        int r = src[e], c = dst[e];
        atomicOr(&A[(size_t)r * NWORDS + (c >> 5)], 1u << (c & 31));
    }
}

// ---------------- boolean row-OR product: Out[i] = OR_{j in P-row(i)} Q-row(j) ----------------
__global__ void bool_mm(const unsigned int* __restrict__ P, const unsigned int* __restrict__ Q,
                        unsigned int* __restrict__ Out)
{
    int row  = blockIdx.x * 4 + (threadIdx.x >> 6);
    int lane = threadIdx.x & 63;
    unsigned acc0 = 0, acc1 = 0;
    const unsigned* prow = P + (size_t)row * NWORDS;
    for (int w = 0; w < NWORDS; ++w) {
        unsigned bits = prow[w];
        while (bits) {
            int b = __ffs(bits) - 1;
            bits &= bits - 1;
            int j = w * 32 + b;
            acc0 |= Q[(size_t)j * NWORDS + lane];
            acc1 |= Q[(size_t)j * NWORDS + 64 + lane];
        }
    }
    Out[(size_t)row * NWORDS + lane]      = acc0;
    Out[(size_t)row * NWORDS + 64 + lane] = acc1;
}

// ---------------- a_out[i] = a_in[i] + coef * sum_{j in Ak-row(i)} a_in[j] ----------------
__global__ void bits_matvec(const unsigned int* __restrict__ Ak, const float* __restrict__ ain,
                            float* __restrict__ aout, float coef)
{
    int row  = blockIdx.x * 4 + (threadIdx.x >> 6);
    int lane = threadIdx.x & 63;
    float s = 0.f;
    #pragma unroll
    for (int h = 0; h < 2; ++h) {
        unsigned bits = Ak[(size_t)row * NWORDS + h * 64 + lane];
        int base = (h * 64 + lane) * 32;
        while (bits) {
            int b = __ffs(bits) - 1;
            bits &= bits - 1;
            s += ain[base + b];
        }
    }
    #pragma unroll
    for (int off = 32; off > 0; off >>= 1) s += __shfl_down(s, off, 64);
    if (lane == 0) aout[row] = ain[row] + coef * s;
}

extern "C" void kernel_launch(void* const* d_in, const int* in_sizes, int n_in,
                              void* d_out, int out_size, void* d_ws, size_t ws_size,
                              hipStream_t stream) {
    const float* coeffs = (const float*)d_in[0];
    const int*   edges  = (const int*)d_in[1];    // [2, E]: src = edges[0:E), dst = edges[E:2E)
    const float* W0     = (const float*)d_in[2];
    const float* b0     = (const float*)d_in[3];
    const float* pa0    = (const float*)d_in[4];
    const float* W1     = (const float*)d_in[5];
    const float* pa1    = (const float*)d_in[6];
    const float* W2     = (const float*)d_in[7];
    const float* pa2    = (const float*)d_in[8];
    const float* Wo     = (const float*)d_in[9];
    const float* bo     = (const float*)d_in[10];
    float* out = (float*)d_out;

    char* ws = (char*)d_ws;
    bf16*  Xb   = (bf16*)(ws + OFF_XB);
    bf16*  W0b  = (bf16*)(ws + OFF_W0B);
    bf16*  W1b  = (bf16*)(ws + OFF_W1B);
    bf16*  W2b  = (bf16*)(ws + OFF_W2B);
    bf16*  x1b  = (bf16*)(ws + OFF_X1);
    bf16*  x2b  = (bf16*)(ws + OFF_X2);
    float* x3f  = (float*)(ws + OFF_X3);
    float* ang  = (float*)(ws + OFF_ANG);
    float* a1v  = (float*)(ws + OFF_A1);
    float* a2v  = (float*)(ws + OFF_A2V);
    unsigned* Ab  = (unsigned*)(ws + OFF_AB);
    unsigned* A2b = (unsigned*)(ws + OFF_A2B);
    unsigned* A3b = (unsigned*)(ws + OFF_A3B);

    const int* srcp = edges;
    const int* dstp = edges + E_EDGES;

    // 1) casts to bf16
    cast_f32_bf16<<<(N_NODES * D_DIM / 4 + 255) / 256, 256, 0, stream>>>(coeffs, Xb, N_NODES * D_DIM);
    cast_f32_bf16<<<(D_DIM * D_DIM / 4 + 255) / 256, 256, 0, stream>>>(W0, W0b, D_DIM * D_DIM);
    cast_f32_bf16<<<(D_DIM * D_DIM / 4 + 255) / 256, 256, 0, stream>>>(W1, W1b, D_DIM * D_DIM);
    cast_f32_bf16<<<(D_DIM * D_DIM / 4 + 255) / 256, 256, 0, stream>>>(W2, W2b, D_DIM * D_DIM);

    // 2) MLP
    dim3 ggrid(N_NODES / 128, D_DIM / 128);
    gemm_bt<true,  false><<<ggrid, 256, 0, stream>>>(Xb,  W0b, x1b, nullptr, b0, pa0);
    gemm_bt<false, false><<<ggrid, 256, 0, stream>>>(x1b, W1b, x2b, nullptr, nullptr, pa1);
    gemm_bt<false, true ><<<ggrid, 256, 0, stream>>>(x2b, W2b, nullptr, x3f, nullptr, pa2);
    matvec_out<<<N_NODES / 4, 256, 0, stream>>>(x3f, Wo, bo, ang, a1v);

    // 3) aggregation
    hop1_edges<<<E_EDGES / 256, 256, 0, stream>>>(srcp, dstp, ang, a1v);
    hipMemsetAsync(Ab, 0, (size_t)N_NODES * NWORDS * 4, stream);
    build_adj<<<E_EDGES / 256, 256, 0, stream>>>(srcp, dstp, Ab);
    bool_mm<<<N_NODES / 4, 256, 0, stream>>>(Ab, Ab,  A2b);   // A^2 = bool(A@A)
    bool_mm<<<N_NODES / 4, 256, 0, stream>>>(Ab, A2b, A3b);   // A^3 = bool(A@A^2) == bool(A^2@A)
    bits_matvec<<<N_NODES / 4, 256, 0, stream>>>(A2b, a1v, a2v, 1.f / 9.f);
    bits_matvec<<<N_NODES / 4, 256, 0, stream>>>(A3b, a2v, out, 1.f / 16.f);
}